// Round 5
// baseline (337.378 us; speedup 1.0000x reference)
//
#include <hip/hip_runtime.h>

#define DIM 64
#define NVOX (DIM * DIM * DIM)

// ---------------------------------------------------------------------------
// Lock-free union-find, atomicMin hooking (Playne & Stepanyan 2018 style).
// Invariant: every stored parent is a <=-index member of the same (merging)
// component; atomicMin only ever lowers values, so stale reads still see a
// valid decreasing chain and every chase terminates. A "failed" hook
// (old != rb) delegates the residual merge (ra, old) to the next loop
// iteration; max(ra,rb) strictly decreases -> guaranteed termination.
// ---------------------------------------------------------------------------
__device__ __forceinline__ void unite(int* L, int a, int b) {
    int ra = a, rb = b;
    while (ra != rb) {
        if (ra > rb) { int t = ra; ra = rb; rb = t; }
        int old = atomicMin(&L[rb], ra);
        if (old == rb || old == ra) break;   // hooked a root / already linked
        rb = old;                            // continue merging (ra, old)
    }
}

// read-only chase (no writes; decreasing chain is valid under concurrency)
__device__ __forceinline__ int chase(const int* __restrict__ L, int p) {
    int q = L[p];
    while (q != p) { p = q; q = L[p]; }
    return p;
}

// ---------------------------------------------------------------------------
// Phase 1 (R5): FULL-ROW run seeding, pure streaming, no CCL work at all.
// Each thread owns 4 x-contiguous voxels; the 16 lanes covering one 64-voxel
// row build the row's 64-bit fg mask with 4x shfl_xor (u64). Every voxel's
// initial label = global index of the head of its x-run (branch-free via
// clz). This pre-merges ALL x-adjacency volume-wide: members point at their
// run head (depth 1), heads point at themselves. parent <= child holds.
// Background = -1. Block (0,0) thread 0 zeroes d_out (ordered before
// finalize's atomics by the dispatch boundaries).
// ---------------------------------------------------------------------------
__global__ __launch_bounds__(256)
void seed_runs(const float* __restrict__ pred, const float* __restrict__ lab,
               int* __restrict__ LP, int* __restrict__ LL,
               float* __restrict__ out) {
    int tix = blockIdx.x * 256 + threadIdx.x;   // 0 .. NVOX/4-1
    if (blockIdx.x == 0 && blockIdx.y == 0 && threadIdx.x == 0) *out = 0.0f;
    int v0 = tix << 2;

    const float* src = blockIdx.y ? lab : pred;
    int* L = blockIdx.y ? LL : LP;

    unsigned nib;
    {
        const float4 f = *reinterpret_cast<const float4*>(src + v0);
        nib  = (unsigned)(f.x > 0.0f);
        nib |= (unsigned)(f.y > 0.0f) << 1;
        nib |= (unsigned)(f.z > 0.0f) << 2;
        nib |= (unsigned)(f.w > 0.0f) << 3;
    }

    // 64-bit row mask across the 16 lanes sharing this row
    int seg = threadIdx.x & 15;                 // 4-voxel segment within row
    unsigned long long rm = (unsigned long long)nib << (seg << 2);
    rm |= __shfl_xor(rm, 1, 64);
    rm |= __shfl_xor(rm, 2, 64);
    rm |= __shfl_xor(rm, 4, 64);
    rm |= __shfl_xor(rm, 8, 64);                // xor 1,2,4,8 stays in 16-group

    int rowstart = v0 & ~63;                    // global index of (0, y, z)
    int xb = seg << 2;

    int lbl[4];
#pragma unroll
    for (int k = 0; k < 4; ++k) {
        int x = xb + k;
        unsigned long long u = ~rm & ((1ull << x) - 1ull);  // zeros below x
        int start = u ? (64 - __clzll(u)) : 0;              // (highest zero)+1
        lbl[k] = ((nib >> k) & 1) ? rowstart + start : -1;
    }
    *reinterpret_cast<int4*>(L + v0) = make_int4(lbl[0], lbl[1], lbl[2], lbl[3]);
}

// ---------------------------------------------------------------------------
// Phase 2 (R5): y/z run linking directly on the global forests.
// Grid (NVOX/1024, field, dir): dir 0 = +y edges, dir 1 = +z edges ->
// max 4 serial unites per thread (half the chain of a combined kernel),
// 1024 blocks of TLP. Loads are coalesced int4 (own row + neighbor row).
// Consecutive-pair skip kills most duplicate (run,run) edges. Stale
// neighbor values are valid same-component members, so a skipped or
// redundant unite is harmless.
// ---------------------------------------------------------------------------
__global__ __launch_bounds__(256)
void link_runs(int* __restrict__ LP, int* __restrict__ LL) {
    int tix = blockIdx.x * 256 + threadIdx.x;   // 0 .. NVOX/4-1
    int v0 = tix << 2;
    int* L = blockIdx.y ? LL : LP;
    int dir = blockIdx.z;                       // 0: +y, 1: +z

    int y = (v0 >> 6) & 63, z = v0 >> 12;
    if (dir ? (z == 63) : (y == 63)) return;
    int off = dir ? 4096 : 64;

    const int4 a4 = *reinterpret_cast<const int4*>(L + v0);
    const int4 b4 = *reinterpret_cast<const int4*>(L + v0 + off);
    int a[4] = { a4.x, a4.y, a4.z, a4.w };
    int b[4] = { b4.x, b4.y, b4.z, b4.w };

    int pa = -2, pb = -2;                       // previous pair (impossible)
#pragma unroll
    for (int k = 0; k < 4; ++k) {
        if (a[k] < 0 || b[k] < 0) continue;
        if (a[k] == pa && b[k] == pb) continue; // same run-pair as last voxel
        unite(L, a[k], b[k]);
        pa = a[k]; pb = b[k];
    }
}

// ---------------------------------------------------------------------------
// 27-bit 3x3x3 mask connectivity via branch-free separable dilation.
// Bit index = z*9 + y*3 + x.
// ---------------------------------------------------------------------------
#define MX_L 0x6DB6DB6u   // result x in {1,2}
#define MX_R 0x36DB6DBu   // result x in {0,1}
#define MY_L 0x7E3F1F8u   // result y in {1,2}
#define MY_R 0x0FC7E3Fu   // result y in {0,1}
#define M27  0x7FFFFFFu

__device__ __forceinline__ unsigned dil26(unsigned m) {
    m |= ((m << 1) & MX_L) | ((m >> 1) & MX_R);
    m |= ((m << 3) & MY_L) | ((m >> 3) & MY_R);
    m |= ((m << 9) & M27)  | (m >> 9);
    return m;
}
__device__ __forceinline__ unsigned dil18(unsigned m) {
    unsigned ax = m | ((m << 1) & MX_L) | ((m >> 1) & MX_R);          // Dx
    unsigned ay = m | ((m << 3) & MY_L) | ((m >> 3) & MY_R);          // Dy
    unsigned dxy = ax | ((ax << 3) & MY_L) | ((ax >> 3) & MY_R);      // DyDx
    unsigned dxz = ax | ((ax << 9) & M27)  | (ax >> 9);               // DzDx
    unsigned dyz = ay | ((ay << 9) & M27)  | (ay >> 9);               // DzDy
    return dxy | dxz | dyz;   // all offsets with >=1 zero component
}

__device__ __forceinline__ bool single18(unsigned m) {
    if (!m) return false;
    unsigned c = m & (~m + 1u);
    for (;;) {
        unsigned n = dil18(c) & m;
        if (n == m) return true;
        if (n == c) return false;
        c = n;
    }
}
__device__ __forceinline__ bool single26(unsigned m) {
    if (!m) return false;
    unsigned c = m & (~m + 1u);
    for (;;) {
        unsigned n = dil26(c) & m;
        if (n == m) return true;
        if (n == c) return false;
        c = n;
    }
}

// ---------------------------------------------------------------------------
// Phase 3: non-simple maps + weighted BCE + mean. (Unchanged, verified.)
// Region 8x8x4 per block (1024 blocks = 4 blocks/CU, 1 voxel/thread/field),
// halo 10x10x6 = 600 ints per field. Halo load batches all independent
// loads, then does the chases. Halo layout: i = hz*100 + hy*10 + hx;
// window corner of (lx,ly,lz) = base, center = base + 111.
// ---------------------------------------------------------------------------
#define HV2 600   // 10*10*6

__global__ __launch_bounds__(256, 4)
void finalize_kernel(const float* __restrict__ pred,
                     const float* __restrict__ lab,
                     const int* __restrict__ LP,
                     const int* __restrict__ LL,
                     float* __restrict__ out) {
    __shared__ int sP[HV2], sL[HV2];
    __shared__ float s_part[4];
    int t = threadIdx.x;
    int b = blockIdx.x;                          // 8 x 8 x 16 regions
    int rx = b & 7, ry = (b >> 3) & 7, rz = b >> 6;
    int x0 = rx << 3, y0 = ry << 3, z0 = rz << 2;

    // batched halo load: all independent loads first, then the chases
    int pv[3], lv[3];
#pragma unroll
    for (int j = 0; j < 3; ++j) {
        int i = t + (j << 8);
        if (i < HV2) {
            int hx = i % 10, rr = i / 10, hy = rr % 10, hz = rr / 10;
            int gx = x0 + hx - 1; gx = gx < 0 ? 0 : (gx > 63 ? 63 : gx);
            int gy = y0 + hy - 1; gy = gy < 0 ? 0 : (gy > 63 ? 63 : gy);
            int gz = z0 + hz - 1; gz = gz < 0 ? 0 : (gz > 63 ? 63 : gz);
            int gv = (gz << 12) | (gy << 6) | gx;
            pv[j] = LP[gv];
            lv[j] = LL[gv];
        }
    }
#pragma unroll
    for (int j = 0; j < 3; ++j) {
        int i = t + (j << 8);
        if (i < HV2) {
            int p = pv[j];
            if (p >= 0) p = chase(LP, p);
            sP[i] = p;
            p = lv[j];
            if (p >= 0) p = chase(LL, p);
            sL[i] = p;
        }
    }
    __syncthreads();

    float acc;
    {
        int l = t;                               // region 8x8x4: 256 voxels
        int lx = l & 7, ly = (l >> 3) & 7, lz = l >> 6;
        int x = x0 | lx, y = y0 | ly, z = z0 | lz;
        int v = (z << 12) | (y << 6) | x;
        int base = lz * 100 + ly * 10 + lx;      // (-1,-1,-1) corner

        bool nsP = false, nsL = false;
        {
            int c = sP[base + 111];              // center
            if (c >= 0) {
                unsigned m1 = 0, m2 = 0; int k = 0;
#pragma unroll
                for (int kz = 0; kz < 3; ++kz)
#pragma unroll
                    for (int ky = 0; ky < 3; ++ky)
#pragma unroll
                        for (int kx = 0; kx < 3; ++kx, ++k) {
                            int w = sP[base + kz * 100 + ky * 10 + kx];
                            m1 |= (unsigned)(w != c) << k;
                            m2 |= (unsigned)(w == c) << k;
                        }
                m2 &= ~(1u << 13);               // drop center
                nsP = !(single18(m1) && single26(m2));
            }
        }
        {
            int c = sL[base + 111];
            if (c >= 0) {
                unsigned m1 = 0, m2 = 0; int k = 0;
#pragma unroll
                for (int kz = 0; kz < 3; ++kz)
#pragma unroll
                    for (int ky = 0; ky < 3; ++ky)
#pragma unroll
                        for (int kx = 0; kx < 3; ++kx, ++k) {
                            int w = sL[base + kz * 100 + ky * 10 + kx];
                            m1 |= (unsigned)(w != c) << k;
                            m2 |= (unsigned)(w == c) << k;
                        }
                m2 &= ~(1u << 13);
                nsL = !(single18(m1) && single26(m2));
            }
        }

        float p = pred[v], lvf = lab[v];
        float cost = fmaxf(p, 0.0f) - p * lvf + log1pf(__expf(-fabsf(p)));
        acc = ((nsP || nsL) ? 5.0f : 1.0f) * cost;
    }

#pragma unroll
    for (int off = 32; off > 0; off >>= 1)
        acc += __shfl_down(acc, off, 64);
    if ((t & 63) == 0) s_part[t >> 6] = acc;
    __syncthreads();
    if (t == 0) {
        float s = s_part[0] + s_part[1] + s_part[2] + s_part[3];
        atomicAdd(out, s * (1.0f / (float)NVOX));
    }
}

extern "C" void kernel_launch(void* const* d_in, const int* in_sizes, int n_in,
                              void* d_out, int out_size, void* d_ws, size_t ws_size,
                              hipStream_t stream) {
    const float* pred = (const float*)d_in[0];   // 'prediction'
    const float* lab  = (const float*)d_in[1];   // 'label'
    float* out = (float*)d_out;

    int* LP = (int*)d_ws;          // NVOX ints
    int* LL = LP + NVOX;           // NVOX ints  (2 MiB total)

    hipLaunchKernelGGL(seed_runs, dim3(NVOX / 1024, 2), dim3(256), 0, stream,
                       pred, lab, LP, LL, out);
    hipLaunchKernelGGL(link_runs, dim3(NVOX / 1024, 2, 2), dim3(256), 0, stream,
                       LP, LL);
    hipLaunchKernelGGL(finalize_kernel, dim3(1024), dim3(256), 0, stream,
                       pred, lab, LP, LL, out);
}

// Round 6
// 107.133 us; speedup vs baseline: 3.1492x; 3.1492x over previous
//
#include <hip/hip_runtime.h>

#define DIM 64
#define NVOX (DIM * DIM * DIM)
#define EPF 53248          // boundary edges per field

// ---------------------------------------------------------------------------
// Lock-free union-find (ECL-CC style) for the GLOBAL forests.
// Invariant: every stored parent is a strictly-smaller-index ancestor ->
// stale (non-coherent L1) reads still see valid ancestors; atomicCAS is the
// coherent ground truth; failed CAS returns a strictly smaller value ->
// guaranteed termination. Path-halving writes keep the forest shallow for
// finalize's chases.
// ---------------------------------------------------------------------------
__device__ __forceinline__ int find_root_link(int* L, int v) {
    for (;;) {
        int p = L[v];
        if (p == v) return v;
        int gp = L[p];
        if (gp == p) return p;
        L[v] = gp;   // path-halving: writes an ancestor, races benign
        v = gp;
    }
}

__device__ __forceinline__ void unite_cas(int* L, int a, int b) {
    int ra = find_root_link(L, a);
    int rb = find_root_link(L, b);
    while (ra != rb) {
        if (ra > rb) { int t = ra; ra = rb; rb = t; }
        int old = atomicCAS(&L[rb], rb, ra);
        if (old == rb) break;            // hooked rb -> ra
        rb = find_root_link(L, old);     // old coherent, strictly < rb
        ra = find_root_link(L, ra);
    }
}

// atomicMin hooking for the LDS tile forests (shallow, coherent, fast).
__device__ __forceinline__ void unite_min(int* L, int a, int b) {
    int ra = a, rb = b;
    while (ra != rb) {
        if (ra > rb) { int t = ra; ra = rb; rb = t; }
        int old = atomicMin(&L[rb], ra);
        if (old == rb || old == ra) break;
        rb = old;
    }
}

// read-only chase (no writes; valid ancestor even under concurrent unites)
__device__ __forceinline__ int chase(const int* __restrict__ L, int p) {
    int q = L[p];
    while (q != p) { p = q; q = L[p]; }
    return p;
}

// ---------------------------------------------------------------------------
// Phase 1: per-tile CCL in LDS. Tile 16x16x8 = 2048 voxels, 512 threads,
// 4 x-contiguous voxels/thread (float4 load, int4 store).
// ROW-RUN SEEDING: each voxel's initial label is the head of its x-run
// (16-bit row mask via 2x shfl_xor OR-reduce + clz); pre-merges all
// x-adjacency, so only y/z unites remain (with consecutive-pair skip).
// Writes global label = global index of tile-local root (tile-local order
// equals global order within a tile -> parent <= child globally).
// Block (0,0) also zeroes d_out (ordered before finalize's atomics by the
// dispatch boundaries).
// ---------------------------------------------------------------------------
__global__ __launch_bounds__(512)
void local_ccl(const float* __restrict__ pred,
               const float* __restrict__ lab,
               int* __restrict__ LP, int* __restrict__ LL,
               float* __restrict__ out) {
    __shared__ int s_lab[2048];
    int t = threadIdx.x;
    if (blockIdx.x == 0 && blockIdx.y == 0 && t == 0) *out = 0.0f;
    int b = blockIdx.x;                         // 128 tiles: 4 x 4 x 8
    int tx = b & 3, ty = (b >> 2) & 3, tz = b >> 4;
    int X0 = tx << 4, Y0 = ty << 4, Z0 = tz << 3;

    const float* src = blockIdx.y ? lab : pred;
    int* Lg = blockIdx.y ? LL : LP;

    int l0 = t << 2;                            // 4 x-contiguous voxels
    int v0 = ((Z0 + (l0 >> 8)) << 12) | ((Y0 + ((l0 >> 4) & 15)) << 6)
           | (X0 + (l0 & 15));

    // load 4 voxels, build per-thread fg nibble
    unsigned nib;
    {
        const float4 f = *reinterpret_cast<const float4*>(src + v0);
        nib  = (unsigned)(f.x > 0.0f);
        nib |= (unsigned)(f.y > 0.0f) << 1;
        nib |= (unsigned)(f.z > 0.0f) << 2;
        nib |= (unsigned)(f.w > 0.0f) << 3;
    }

    // 16-bit row mask: OR nibbles across the aligned 4-thread group
    unsigned rm = nib << ((t & 3) << 2);
    rm |= __shfl_xor(rm, 1, 64);
    rm |= __shfl_xor(rm, 2, 64);

    int rowbase = l0 & ~15;                     // row start voxel (local)
    int xbase = l0 & 15;                        // this thread's first x in row

    // seed labels = run head (branch-free)
    {
        int4 s;
        int lbl[4];
#pragma unroll
        for (int k = 0; k < 4; ++k) {
            int xpos = xbase + k;
            unsigned u = ~rm & ((1u << xpos) - 1u);   // zeros strictly below
            int start = u ? (32 - __clz(u)) : 0;      // (highest zero)+1
            lbl[k] = ((nib >> k) & 1) ? rowbase + start : -1;
        }
        s.x = lbl[0]; s.y = lbl[1]; s.z = lbl[2]; s.w = lbl[3];
        *reinterpret_cast<int4*>(&s_lab[l0]) = s;
    }
    __syncthreads();

    // y/z unites only (x handled by run seeding), with repeated-pair skip
    {
        int py_a = -2, py_b = -2;               // previous y-pair (impossible)
        int pz_a = -2, pz_b = -2;
#pragma unroll
        for (int k = 0; k < 4; ++k) {
            if (!((nib >> k) & 1)) continue;
            int l = l0 + k;
            int a = s_lab[l];                   // this run's head (stable)
            int ly = (l >> 4) & 15, lz = l >> 8;
            if (ly < 15) {
                int nb = s_lab[l + 16];
                if (nb >= 0 && !(a == py_a && nb == py_b)) {
                    unite_min(s_lab, a, nb);
                    py_a = a; py_b = nb;
                }
            }
            if (lz < 7) {
                int nb = s_lab[l + 256];
                if (nb >= 0 && !(a == pz_a && nb == pz_b)) {
                    unite_min(s_lab, a, nb);
                    pz_a = a; pz_b = nb;
                }
            }
        }
    }
    __syncthreads();

    // chase to tile root, write global labels
    {
        int rr[4];
#pragma unroll
        for (int k = 0; k < 4; ++k) {
            int g = -1;
            if ((nib >> k) & 1) {
                int p = s_lab[l0 + k];
                while (s_lab[p] != p) p = s_lab[p];  // read-only chase
                g = ((Z0 + (p >> 8)) << 12) | ((Y0 + ((p >> 4) & 15)) << 6)
                  | (X0 + (p & 15));
            }
            rr[k] = g;
        }
        *reinterpret_cast<int4*>(Lg + v0) = make_int4(rr[0], rr[1], rr[2], rr[3]);
    }
}

// ---------------------------------------------------------------------------
// Phase 2: compact cross-tile edge list, one thread per geometric edge,
// one FIELD per blockIdx.y (halves the per-thread dependent-chase chain,
// doubles TLP). Dedupe on the RAW tile-root pair BEFORE chasing, then on
// final roots before unite. Raw labels are stable tile roots; any stored
// value is a valid ancestor, so a missed dedupe is only a tiny redundancy,
// never an error. CAS unite with path-halving keeps the global forest
// shallow for finalize's chases.
// ---------------------------------------------------------------------------
__global__ __launch_bounds__(256)
void boundary_link(int* __restrict__ LP, int* __restrict__ LL) {
    int r = blockIdx.x * blockDim.x + threadIdx.x;   // 0..EPF-1
    int* L = blockIdx.y ? LL : LP;

    int v, n;
    if (r < 12288) {                             // x-faces: planes 15,31,47
        int plane = 15 + ((r >> 12) << 4);
        int ij = r & 4095;                       // y = ij&63 (lane-consecutive)
        v = ((ij >> 6) << 12) | ((ij & 63) << 6) | plane;
        n = v + 1;
    } else if (r < 24576) {                      // y-faces: planes 15,31,47
        int r2 = r - 12288;
        int plane = 15 + ((r2 >> 12) << 4);
        int ij = r2 & 4095;                      // x = ij&63, z = ij>>6
        v = ((ij >> 6) << 12) | (plane << 6) | (ij & 63);
        n = v + 64;
    } else {                                     // z-faces: planes 7..55
        int r3 = r - 24576;
        int plane = 7 + ((r3 >> 12) << 3);
        int ij = r3 & 4095;                      // x = ij&63, y = ij>>6
        v = (plane << 12) | ((ij >> 6) << 6) | (ij & 63);
        n = v + 4096;
    }

    int lane = threadIdx.x & 63;

    int pa = L[v], pb = L[n];
    bool go = (pa >= 0) & (pb >= 0);

    // raw-pair dedupe (kills the chase for run-duplicates)
    int xpa = __shfl_up(pa, 1, 64), xpb = __shfl_up(pb, 1, 64);
    if (lane && xpa == pa && xpb == pb) go = false;

    int r0 = -1, r1 = -1;
    if (go) {
        int u0 = find_root_link(L, pa), u1 = find_root_link(L, pb);
        r0 = min(u0, u1); r1 = max(u0, u1);
    }

    // root-pair dedupe (different raw pairs may share final roots)
    int q0 = __shfl_up(r0, 1, 64), q1 = __shfl_up(r1, 1, 64);
    bool dup = lane && (q0 == r0) && (q1 == r1);

    if (r0 >= 0 && r0 != r1 && !dup) unite_cas(L, r0, r1);
}

// ---------------------------------------------------------------------------
// 27-bit 3x3x3 mask connectivity via branch-free separable dilation.
// Bit index = z*9 + y*3 + x.
// ---------------------------------------------------------------------------
#define MX_L 0x6DB6DB6u   // result x in {1,2}
#define MX_R 0x36DB6DBu   // result x in {0,1}
#define MY_L 0x7E3F1F8u   // result y in {1,2}
#define MY_R 0x0FC7E3Fu   // result y in {0,1}
#define M27  0x7FFFFFFu

__device__ __forceinline__ unsigned dil26(unsigned m) {
    m |= ((m << 1) & MX_L) | ((m >> 1) & MX_R);
    m |= ((m << 3) & MY_L) | ((m >> 3) & MY_R);
    m |= ((m << 9) & M27)  | (m >> 9);
    return m;
}
__device__ __forceinline__ unsigned dil18(unsigned m) {
    unsigned ax = m | ((m << 1) & MX_L) | ((m >> 1) & MX_R);          // Dx
    unsigned ay = m | ((m << 3) & MY_L) | ((m >> 3) & MY_R);          // Dy
    unsigned dxy = ax | ((ax << 3) & MY_L) | ((ax >> 3) & MY_R);      // DyDx
    unsigned dxz = ax | ((ax << 9) & M27)  | (ax >> 9);               // DzDx
    unsigned dyz = ay | ((ay << 9) & M27)  | (ay >> 9);               // DzDy
    return dxy | dxz | dyz;   // all offsets with >=1 zero component
}

__device__ __forceinline__ bool single18(unsigned m) {
    if (!m) return false;
    unsigned c = m & (~m + 1u);
    for (;;) {
        unsigned n = dil18(c) & m;
        if (n == m) return true;
        if (n == c) return false;
        c = n;
    }
}
__device__ __forceinline__ bool single26(unsigned m) {
    if (!m) return false;
    unsigned c = m & (~m + 1u);
    for (;;) {
        unsigned n = dil26(c) & m;
        if (n == m) return true;
        if (n == c) return false;
        c = n;
    }
}

// ---------------------------------------------------------------------------
// Phase 3: non-simple maps + weighted BCE + mean.
// Region 8x8x4 per block (1024 blocks = 4 blocks/CU, 1 voxel/thread/field),
// halo 10x10x6 = 600 entries. R6: halo packed as int2 {P,L} -> the 27-point
// mask build reads ONE ds_read_b64 per window cell for BOTH fields (27
// LDS issues instead of 54), and only the != masks are built (m2 is the
// complement of m1 within M27: every non-center cell is either == or !=,
// and m1's center bit is always 0). Halo load batches all independent
// loads, then does the chases.
// Halo layout: i = hz*100 + hy*10 + hx; window corner of (lx,ly,lz) = base,
// center = base + 111.
// ---------------------------------------------------------------------------
#define HV2 600   // 10*10*6

__global__ __launch_bounds__(256, 4)
void finalize_kernel(const float* __restrict__ pred,
                     const float* __restrict__ lab,
                     const int* __restrict__ LP,
                     const int* __restrict__ LL,
                     float* __restrict__ out) {
    __shared__ int2 sPL[HV2];
    __shared__ float s_part[4];
    int t = threadIdx.x;
    int b = blockIdx.x;                          // 8 x 8 x 16 regions
    int rx = b & 7, ry = (b >> 3) & 7, rz = b >> 6;
    int x0 = rx << 3, y0 = ry << 3, z0 = rz << 2;

    // batched halo load: all independent loads first, then the chases
    int pv[3], lv[3];
#pragma unroll
    for (int j = 0; j < 3; ++j) {
        int i = t + (j << 8);
        if (i < HV2) {
            int hx = i % 10, rr = i / 10, hy = rr % 10, hz = rr / 10;
            int gx = x0 + hx - 1; gx = gx < 0 ? 0 : (gx > 63 ? 63 : gx);
            int gy = y0 + hy - 1; gy = gy < 0 ? 0 : (gy > 63 ? 63 : gy);
            int gz = z0 + hz - 1; gz = gz < 0 ? 0 : (gz > 63 ? 63 : gz);
            int gv = (gz << 12) | (gy << 6) | gx;
            pv[j] = LP[gv];
            lv[j] = LL[gv];
        }
    }
#pragma unroll
    for (int j = 0; j < 3; ++j) {
        int i = t + (j << 8);
        if (i < HV2) {
            int p = pv[j];
            if (p >= 0) p = chase(LP, p);
            int l = lv[j];
            if (l >= 0) l = chase(LL, l);
            sPL[i] = make_int2(p, l);
        }
    }
    __syncthreads();

    float acc;
    {
        int l = t;                               // region 8x8x4: 256 voxels
        int lx = l & 7, ly = (l >> 3) & 7, lz = l >> 6;
        int x = x0 | lx, y = y0 | ly, z = z0 | lz;
        int v = (z << 12) | (y << 6) | x;
        int base = lz * 100 + ly * 10 + lx;      // (-1,-1,-1) corner

        const int2 c2 = sPL[base + 111];         // centers {P,L}
        unsigned m1P = 0, m1L = 0;
        int k = 0;
#pragma unroll
        for (int kz = 0; kz < 3; ++kz)
#pragma unroll
            for (int ky = 0; ky < 3; ++ky)
#pragma unroll
                for (int kx = 0; kx < 3; ++kx, ++k) {
                    const int2 w2 = sPL[base + kz * 100 + ky * 10 + kx];
                    m1P |= (unsigned)(w2.x != c2.x) << k;
                    m1L |= (unsigned)(w2.y != c2.y) << k;
                }

        bool nsP = false, nsL = false;
        if (c2.x >= 0) {
            unsigned m2 = ~m1P & (M27 & ~(1u << 13));   // ==-mask, no center
            nsP = !(single18(m1P) && single26(m2));
        }
        if (c2.y >= 0) {
            unsigned m2 = ~m1L & (M27 & ~(1u << 13));
            nsL = !(single18(m1L) && single26(m2));
        }

        float p = pred[v], lvf = lab[v];
        float cost = fmaxf(p, 0.0f) - p * lvf + log1pf(__expf(-fabsf(p)));
        acc = ((nsP || nsL) ? 5.0f : 1.0f) * cost;
    }

#pragma unroll
    for (int off = 32; off > 0; off >>= 1)
        acc += __shfl_down(acc, off, 64);
    if ((t & 63) == 0) s_part[t >> 6] = acc;
    __syncthreads();
    if (t == 0) {
        float s = s_part[0] + s_part[1] + s_part[2] + s_part[3];
        atomicAdd(out, s * (1.0f / (float)NVOX));
    }
}

extern "C" void kernel_launch(void* const* d_in, const int* in_sizes, int n_in,
                              void* d_out, int out_size, void* d_ws, size_t ws_size,
                              hipStream_t stream) {
    const float* pred = (const float*)d_in[0];   // 'prediction'
    const float* lab  = (const float*)d_in[1];   // 'label'
    float* out = (float*)d_out;

    int* LP = (int*)d_ws;          // NVOX ints
    int* LL = LP + NVOX;           // NVOX ints  (2 MiB total)

    hipLaunchKernelGGL(local_ccl, dim3(128, 2), dim3(512), 0, stream,
                       pred, lab, LP, LL, out);
    hipLaunchKernelGGL(boundary_link, dim3(EPF / 256, 2), dim3(256), 0, stream,
                       LP, LL);
    hipLaunchKernelGGL(finalize_kernel, dim3(1024), dim3(256), 0, stream,
                       pred, lab, LP, LL, out);
}

// Round 7
// 105.169 us; speedup vs baseline: 3.2080x; 1.0187x over previous
//
#include <hip/hip_runtime.h>

#define DIM 64
#define NVOX (DIM * DIM * DIM)
#define EPF 53248          // boundary edges per field

// ---------------------------------------------------------------------------
// Lock-free union-find, atomicMin hooking (Playne & Stepanyan 2018 style).
// Invariant: every stored parent is a <=-index member of the same (merging)
// component; atomicMin only ever lowers values, so stale reads still see a
// valid decreasing chain and every chase terminates. A "failed" hook
// (old != rb) delegates the residual merge (ra, old) to the next loop
// iteration; max(ra,rb) strictly decreases -> guaranteed termination.
// Works identically on LDS and global arrays. Best-measured config (R4).
// ---------------------------------------------------------------------------
__device__ __forceinline__ void unite(int* L, int a, int b) {
    int ra = a, rb = b;
    while (ra != rb) {
        if (ra > rb) { int t = ra; ra = rb; rb = t; }
        int old = atomicMin(&L[rb], ra);
        if (old == rb || old == ra) break;   // hooked a root / already linked
        rb = old;                            // continue merging (ra, old)
    }
}

// read-only chase (no writes; decreasing chain is valid under concurrency)
__device__ __forceinline__ int chase(const int* __restrict__ L, int p) {
    int q = L[p];
    while (q != p) { p = q; q = L[p]; }
    return p;
}

// ---------------------------------------------------------------------------
// Phase 1: per-tile CCL in LDS. Tile 16x16x8 = 2048 voxels, 512 threads,
// 4 x-contiguous voxels/thread (float4 load, int4 store).
// ROW-RUN SEEDING: each voxel's initial label is the head of its x-run
// (16-bit row mask via 2x shfl_xor OR-reduce + clz); pre-merges all
// x-adjacency, so only y/z unites remain (with consecutive-pair skip).
// R7: the unite phase uses the REGISTER copy of the run head (any component
// member is a valid unite argument) -- removes a dependent LDS read/voxel.
// Writes global label = global index of tile-local root (tile-local order
// equals global order within a tile -> parent <= child globally).
// Block (0,0) also zeroes d_out (ordered before finalize's atomics by the
// dispatch boundaries).
// ---------------------------------------------------------------------------
__global__ __launch_bounds__(512)
void local_ccl(const float* __restrict__ pred,
               const float* __restrict__ lab,
               int* __restrict__ LP, int* __restrict__ LL,
               float* __restrict__ out) {
    __shared__ int s_lab[2048];
    int t = threadIdx.x;
    if (blockIdx.x == 0 && blockIdx.y == 0 && t == 0) *out = 0.0f;
    int b = blockIdx.x;                         // 128 tiles: 4 x 4 x 8
    int tx = b & 3, ty = (b >> 2) & 3, tz = b >> 4;
    int X0 = tx << 4, Y0 = ty << 4, Z0 = tz << 3;

    const float* src = blockIdx.y ? lab : pred;
    int* Lg = blockIdx.y ? LL : LP;

    int l0 = t << 2;                            // 4 x-contiguous voxels
    int v0 = ((Z0 + (l0 >> 8)) << 12) | ((Y0 + ((l0 >> 4) & 15)) << 6)
           | (X0 + (l0 & 15));

    // load 4 voxels, build per-thread fg nibble
    unsigned nib;
    {
        const float4 f = *reinterpret_cast<const float4*>(src + v0);
        nib  = (unsigned)(f.x > 0.0f);
        nib |= (unsigned)(f.y > 0.0f) << 1;
        nib |= (unsigned)(f.z > 0.0f) << 2;
        nib |= (unsigned)(f.w > 0.0f) << 3;
    }

    // 16-bit row mask: OR nibbles across the aligned 4-thread group
    unsigned rm = nib << ((t & 3) << 2);
    rm |= __shfl_xor(rm, 1, 64);
    rm |= __shfl_xor(rm, 2, 64);

    int rowbase = l0 & ~15;                     // row start voxel (local)
    int xbase = l0 & 15;                        // this thread's first x in row

    // seed labels = run head (branch-free); keep heads in registers
    int lbl[4];
    {
#pragma unroll
        for (int k = 0; k < 4; ++k) {
            int xpos = xbase + k;
            unsigned u = ~rm & ((1u << xpos) - 1u);   // zeros strictly below
            int start = u ? (32 - __clz(u)) : 0;      // (highest zero)+1
            lbl[k] = ((nib >> k) & 1) ? rowbase + start : -1;
        }
        *reinterpret_cast<int4*>(&s_lab[l0]) =
            make_int4(lbl[0], lbl[1], lbl[2], lbl[3]);
    }
    __syncthreads();

    // y/z unites only (x handled by run seeding), with repeated-pair skip;
    // 'a' comes from the register seed (valid component member)
    {
        int py_a = -2, py_b = -2;               // previous y-pair (impossible)
        int pz_a = -2, pz_b = -2;
#pragma unroll
        for (int k = 0; k < 4; ++k) {
            int a = lbl[k];
            if (a < 0) continue;
            int l = l0 + k;
            int ly = (l >> 4) & 15, lz = l >> 8;
            if (ly < 15) {
                int nb = s_lab[l + 16];
                if (nb >= 0 && !(a == py_a && nb == py_b)) {
                    unite(s_lab, a, nb);
                    py_a = a; py_b = nb;
                }
            }
            if (lz < 7) {
                int nb = s_lab[l + 256];
                if (nb >= 0 && !(a == pz_a && nb == pz_b)) {
                    unite(s_lab, a, nb);
                    pz_a = a; pz_b = nb;
                }
            }
        }
    }
    __syncthreads();

    // chase to tile root, write global labels
    {
        int rr[4];
#pragma unroll
        for (int k = 0; k < 4; ++k) {
            int g = -1;
            if ((nib >> k) & 1) {
                int p = s_lab[l0 + k];
                while (s_lab[p] != p) p = s_lab[p];  // read-only chase
                g = ((Z0 + (p >> 8)) << 12) | ((Y0 + ((p >> 4) & 15)) << 6)
                  | (X0 + (p & 15));
            }
            rr[k] = g;
        }
        *reinterpret_cast<int4*>(Lg + v0) = make_int4(rr[0], rr[1], rr[2], rr[3]);
    }
}

// ---------------------------------------------------------------------------
// Phase 2: compact cross-tile edge list, one thread per geometric edge,
// one FIELD per blockIdx.y (halves the per-thread dependent-chase chain,
// doubles TLP). Dedupe on the RAW tile-root pair BEFORE chasing, then on
// final roots before unite. Raw labels are stable tile roots; any stored
// value is a valid component member, so a missed dedupe is only a tiny
// redundancy, never an error. (Exact R4 config -- best measured.)
// ---------------------------------------------------------------------------
__global__ __launch_bounds__(256)
void boundary_link(int* __restrict__ LP, int* __restrict__ LL) {
    int r = blockIdx.x * blockDim.x + threadIdx.x;   // 0..EPF-1
    int* L = blockIdx.y ? LL : LP;

    int v, n;
    if (r < 12288) {                             // x-faces: planes 15,31,47
        int plane = 15 + ((r >> 12) << 4);
        int ij = r & 4095;                       // y = ij&63 (lane-consecutive)
        v = ((ij >> 6) << 12) | ((ij & 63) << 6) | plane;
        n = v + 1;
    } else if (r < 24576) {                      // y-faces: planes 15,31,47
        int r2 = r - 12288;
        int plane = 15 + ((r2 >> 12) << 4);
        int ij = r2 & 4095;                      // x = ij&63, z = ij>>6
        v = ((ij >> 6) << 12) | (plane << 6) | (ij & 63);
        n = v + 64;
    } else {                                     // z-faces: planes 7..55
        int r3 = r - 24576;
        int plane = 7 + ((r3 >> 12) << 3);
        int ij = r3 & 4095;                      // x = ij&63, y = ij>>6
        v = (plane << 12) | ((ij >> 6) << 6) | (ij & 63);
        n = v + 4096;
    }

    int lane = threadIdx.x & 63;

    int pa = L[v], pb = L[n];
    bool go = (pa >= 0) & (pb >= 0);

    // raw-pair dedupe (kills the chase for run-duplicates)
    int xpa = __shfl_up(pa, 1, 64), xpb = __shfl_up(pb, 1, 64);
    if (lane && xpa == pa && xpb == pb) go = false;

    int r0 = -1, r1 = -1;
    if (go) {
        int u0 = chase(L, pa), u1 = chase(L, pb);
        r0 = min(u0, u1); r1 = max(u0, u1);
    }

    // root-pair dedupe (different raw pairs may share final roots)
    int q0 = __shfl_up(r0, 1, 64), q1 = __shfl_up(r1, 1, 64);
    bool dup = lane && (q0 == r0) && (q1 == r1);

    if (r0 >= 0 && r0 != r1 && !dup) unite(L, r0, r1);
}

// ---------------------------------------------------------------------------
// 27-bit 3x3x3 mask connectivity via branch-free separable dilation.
// Bit index = z*9 + y*3 + x.
// ---------------------------------------------------------------------------
#define MX_L 0x6DB6DB6u   // result x in {1,2}
#define MX_R 0x36DB6DBu   // result x in {0,1}
#define MY_L 0x7E3F1F8u   // result y in {1,2}
#define MY_R 0x0FC7E3Fu   // result y in {0,1}
#define M27  0x7FFFFFFu

__device__ __forceinline__ unsigned dil26(unsigned m) {
    m |= ((m << 1) & MX_L) | ((m >> 1) & MX_R);
    m |= ((m << 3) & MY_L) | ((m >> 3) & MY_R);
    m |= ((m << 9) & M27)  | (m >> 9);
    return m;
}
__device__ __forceinline__ unsigned dil18(unsigned m) {
    unsigned ax = m | ((m << 1) & MX_L) | ((m >> 1) & MX_R);          // Dx
    unsigned ay = m | ((m << 3) & MY_L) | ((m >> 3) & MY_R);          // Dy
    unsigned dxy = ax | ((ax << 3) & MY_L) | ((ax >> 3) & MY_R);      // DyDx
    unsigned dxz = ax | ((ax << 9) & M27)  | (ax >> 9);               // DzDx
    unsigned dyz = ay | ((ay << 9) & M27)  | (ay >> 9);               // DzDy
    return dxy | dxz | dyz;   // all offsets with >=1 zero component
}

__device__ __forceinline__ bool single18(unsigned m) {
    if (!m) return false;
    unsigned c = m & (~m + 1u);
    for (;;) {
        unsigned n = dil18(c) & m;
        if (n == m) return true;
        if (n == c) return false;
        c = n;
    }
}
__device__ __forceinline__ bool single26(unsigned m) {
    if (!m) return false;
    unsigned c = m & (~m + 1u);
    for (;;) {
        unsigned n = dil26(c) & m;
        if (n == m) return true;
        if (n == c) return false;
        c = n;
    }
}

// ---------------------------------------------------------------------------
// Phase 3: non-simple maps + weighted BCE + mean.
// Region 8x8x4 per block (1024 blocks = 4 blocks/CU, 1 voxel/thread/field),
// halo 10x10x6 = 600 entries packed as int2 {P,L}: the 27-point mask build
// reads ONE ds_read_b64 per window cell for BOTH fields (27 LDS issues
// instead of 54), and only the != masks are built (m2 = complement of m1
// within M27 minus the center bit). Halo load batches all independent
// loads, then does the chases.
// Halo layout: i = hz*100 + hy*10 + hx; window corner of (lx,ly,lz) = base,
// center = base + 111.
// ---------------------------------------------------------------------------
#define HV2 600   // 10*10*6

__global__ __launch_bounds__(256, 4)
void finalize_kernel(const float* __restrict__ pred,
                     const float* __restrict__ lab,
                     const int* __restrict__ LP,
                     const int* __restrict__ LL,
                     float* __restrict__ out) {
    __shared__ int2 sPL[HV2];
    __shared__ float s_part[4];
    int t = threadIdx.x;
    int b = blockIdx.x;                          // 8 x 8 x 16 regions
    int rx = b & 7, ry = (b >> 3) & 7, rz = b >> 6;
    int x0 = rx << 3, y0 = ry << 3, z0 = rz << 2;

    // batched halo load: all independent loads first, then the chases
    int pv[3], lv[3];
#pragma unroll
    for (int j = 0; j < 3; ++j) {
        int i = t + (j << 8);
        if (i < HV2) {
            int hx = i % 10, rr = i / 10, hy = rr % 10, hz = rr / 10;
            int gx = x0 + hx - 1; gx = gx < 0 ? 0 : (gx > 63 ? 63 : gx);
            int gy = y0 + hy - 1; gy = gy < 0 ? 0 : (gy > 63 ? 63 : gy);
            int gz = z0 + hz - 1; gz = gz < 0 ? 0 : (gz > 63 ? 63 : gz);
            int gv = (gz << 12) | (gy << 6) | gx;
            pv[j] = LP[gv];
            lv[j] = LL[gv];
        }
    }
#pragma unroll
    for (int j = 0; j < 3; ++j) {
        int i = t + (j << 8);
        if (i < HV2) {
            int p = pv[j];
            if (p >= 0) p = chase(LP, p);
            int l = lv[j];
            if (l >= 0) l = chase(LL, l);
            sPL[i] = make_int2(p, l);
        }
    }
    __syncthreads();

    float acc;
    {
        int l = t;                               // region 8x8x4: 256 voxels
        int lx = l & 7, ly = (l >> 3) & 7, lz = l >> 6;
        int x = x0 | lx, y = y0 | ly, z = z0 | lz;
        int v = (z << 12) | (y << 6) | x;
        int base = lz * 100 + ly * 10 + lx;      // (-1,-1,-1) corner

        const int2 c2 = sPL[base + 111];         // centers {P,L}
        unsigned m1P = 0, m1L = 0;
        int k = 0;
#pragma unroll
        for (int kz = 0; kz < 3; ++kz)
#pragma unroll
            for (int ky = 0; ky < 3; ++ky)
#pragma unroll
                for (int kx = 0; kx < 3; ++kx, ++k) {
                    const int2 w2 = sPL[base + kz * 100 + ky * 10 + kx];
                    m1P |= (unsigned)(w2.x != c2.x) << k;
                    m1L |= (unsigned)(w2.y != c2.y) << k;
                }

        bool nsP = false, nsL = false;
        if (c2.x >= 0) {
            unsigned m2 = ~m1P & (M27 & ~(1u << 13));   // ==-mask, no center
            nsP = !(single18(m1P) && single26(m2));
        }
        if (c2.y >= 0) {
            unsigned m2 = ~m1L & (M27 & ~(1u << 13));
            nsL = !(single18(m1L) && single26(m2));
        }

        float p = pred[v], lvf = lab[v];
        float cost = fmaxf(p, 0.0f) - p * lvf + log1pf(__expf(-fabsf(p)));
        acc = ((nsP || nsL) ? 5.0f : 1.0f) * cost;
    }

#pragma unroll
    for (int off = 32; off > 0; off >>= 1)
        acc += __shfl_down(acc, off, 64);
    if ((t & 63) == 0) s_part[t >> 6] = acc;
    __syncthreads();
    if (t == 0) {
        float s = s_part[0] + s_part[1] + s_part[2] + s_part[3];
        atomicAdd(out, s * (1.0f / (float)NVOX));
    }
}

extern "C" void kernel_launch(void* const* d_in, const int* in_sizes, int n_in,
                              void* d_out, int out_size, void* d_ws, size_t ws_size,
                              hipStream_t stream) {
    const float* pred = (const float*)d_in[0];   // 'prediction'
    const float* lab  = (const float*)d_in[1];   // 'label'
    float* out = (float*)d_out;

    int* LP = (int*)d_ws;          // NVOX ints
    int* LL = LP + NVOX;           // NVOX ints  (2 MiB total)

    hipLaunchKernelGGL(local_ccl, dim3(128, 2), dim3(512), 0, stream,
                       pred, lab, LP, LL, out);
    hipLaunchKernelGGL(boundary_link, dim3(EPF / 256, 2), dim3(256), 0, stream,
                       LP, LL);
    hipLaunchKernelGGL(finalize_kernel, dim3(1024), dim3(256), 0, stream,
                       pred, lab, LP, LL, out);
}